// Round 4
// baseline (79.751 us; speedup 1.0000x reference)
//
#include <hip/hip_runtime.h>
#include <math.h>

#define N_BINS 256
#define TAU 0.01f
#define EPS 1e-10f
#define HW (512*512)
#define Q 4081            // quant levels; Q-1 = 4080 = 16*255 so t_q - b_j = (q-16j)/4080
#define QSTRIDE 4096
#define MWIN 208          // |q-16j| <= 208 -> dropped weight exp(-13) ~ 2e-6 (negligible)
#define WTAB (2*MWIN+1)   // 417
#define WPADN 432         // 16*27, zero-padded tail
#define NP 27             // taps per phase: m = 16*(p-13)+r
#define CFP_STRIDE 289    // 282 used; 289 makes bank = (r + 16t + k) % 32 -> 2-way (free)

// One fused kernel: hist -> grid barrier -> per-block redundant CDF+LUT -> equalize.
// Grid = 64*B blocks (<= 256), 256 threads. Co-residency: 56 KB LDS -> >=1 block/CU,
// grid <= CU count -> all blocks resident -> software barrier is deadlock-free.
__global__ __launch_bounds__(256) void fused_equalize(
    const float* __restrict__ x, unsigned int* __restrict__ c,
    unsigned int* __restrict__ flags, float* __restrict__ out, int nblk)
{
    __shared__ float cfp[16 * CFP_STRIDE];   // phase-transposed padded counts
    __shared__ float ph[256 * 17];           // conv partials [j][r], stride 17 (2-way banks)
    __shared__ union { unsigned int lh[QSTRIDE]; float Tl[QSTRIDE]; } U;  // hist, later LUT
    __shared__ float wtE[WPADN];
    __shared__ float cdfnp[284];             // cdfn[j] at idx j+13, zero-padded
    __shared__ float onesp[284];             // 1 for valid j, 0 in pads (denominator mask)
    __shared__ float wsum[4];
    __shared__ float h0s;

    const int tid = threadIdx.x;
    const int bid = blockIdx.x;
    const int b   = bid >> 6;                // batch
    const int s   = bid & 63;                // pixel slice within batch
    const int r   = tid & 15;                // phase (spans 16 within a wave)
    const int t   = tid >> 4;                // chunk  (spans 4 within a wave)

    // ---- Phase 1: global pixel loads (kept in registers) + LDS init ----
    const float4* xb = (const float4*)(x + (size_t)b * HW + (size_t)s * 4096);
    float4 px[4];
#pragma unroll
    for (int i = 0; i < 4; ++i) px[i] = xb[i * 256 + tid];

    for (int i = tid; i < 16 * CFP_STRIDE; i += 256) cfp[i] = 0.f;
    for (int i = tid; i < 284; i += 256) {
        cdfnp[i] = 0.f;
        onesp[i] = (i >= 13 && i < 269) ? 1.f : 0.f;
    }
    for (int i = tid; i < WPADN; i += 256) {
        const float d = (float)(i - MWIN) * (1.0f / 4080.f);
        wtE[i] = (i < WTAB) ? __expf(-d * d * (1.0f / (2.0f * TAU * TAU))) : 0.f;
    }
    for (int i = tid; i < QSTRIDE; i += 256) U.lh[i] = 0u;
    __syncthreads();

    // ---- Phase 2: LDS hard histogram ----
#pragma unroll
    for (int i = 0; i < 4; ++i) {
        const float4 v = px[i];
        int q0 = __float2int_rn(v.x * 4080.f);
        int q1 = __float2int_rn(v.y * 4080.f);
        int q2 = __float2int_rn(v.z * 4080.f);
        int q3 = __float2int_rn(v.w * 4080.f);
        q0 = min(max(q0, 0), Q - 1); q1 = min(max(q1, 0), Q - 1);
        q2 = min(max(q2, 0), Q - 1); q3 = min(max(q3, 0), Q - 1);
        atomicAdd(&U.lh[q0], 1u); atomicAdd(&U.lh[q1], 1u);
        atomicAdd(&U.lh[q2], 1u); atomicAdd(&U.lh[q3], 1u);
    }
    __syncthreads();

    // ---- Phase 3: merge to global (device-scope atomics), signal arrival ----
    for (int k = 0; k < 16; ++k) {
        const int i = tid + (((k + bid) & 15) << 8);
        const unsigned int cnt = U.lh[i];
        if (cnt) atomicAdd(&c[b * QSTRIDE + i], cnt);
    }
    __syncthreads();   // drains vmcnt: all this block's atomics acked at coherence point
    if (tid == 0)
        __hip_atomic_store(&flags[bid], 1u, __ATOMIC_RELEASE, __HIP_MEMORY_SCOPE_AGENT);

    // ---- Phase 4: grid barrier (flags zeroed by the per-launch memset) ----
    for (int i = tid; i < nblk; i += 256) {
        while (__hip_atomic_load(&flags[i], __ATOMIC_RELAXED, __HIP_MEMORY_SCOPE_AGENT) != 1u)
            __builtin_amdgcn_s_sleep(2);
    }
    __syncthreads();
    __builtin_amdgcn_fence(__ATOMIC_ACQUIRE, "agent");

    // ---- Phase 5: load merged counts, phase-transposed into cfp ----
#pragma unroll
    for (int i = 0; i < 16; ++i) {
        const int q = i * 256 + tid;
        const unsigned int cv =
            __hip_atomic_load(&c[b * QSTRIDE + q], __ATOMIC_RELAXED, __HIP_MEMORY_SCOPE_AGENT);
        cfp[(q & 15) * CFP_STRIDE + (q >> 4) + 13] = (float)cv;  // zero pads already set
    }
    __syncthreads();

    // ---- Phase 6: soft hist conv, register-blocked per (r, t) ----
    // hist[j] = sum_p sum_r wtE[16p+r] * cnt[16(j+p-13)+r]
    {
        float creg[42];
        const float* cbase = &cfp[r * CFP_STRIDE + 16 * t];
#pragma unroll
        for (int k = 0; k < 42; ++k) creg[k] = cbase[k];
        float acc[16];
#pragma unroll
        for (int uu = 0; uu < 16; ++uu) acc[uu] = 0.f;
#pragma unroll
        for (int p = 0; p < NP; ++p) {
            const float w = wtE[16 * p + r];
#pragma unroll
            for (int uu = 0; uu < 16; ++uu) acc[uu] += w * creg[uu + p];
        }
#pragma unroll
        for (int uu = 0; uu < 16; ++uu) ph[(16 * t + uu) * 17 + r] = acc[uu];
    }
    __syncthreads();

    // ---- Phase 7: reduce phases, wave-shuffle scan, cdf normalization ----
    float hv = 0.f;
#pragma unroll
    for (int rr = 0; rr < 16; ++rr) hv += ph[tid * 17 + rr];
    float val = hv;
    const int lane = tid & 63;
#pragma unroll
    for (int d = 1; d < 64; d <<= 1) {
        const float n = __shfl_up(val, (unsigned)d, 64);
        if (lane >= d) val += n;
    }
    if (lane == 63) wsum[tid >> 6] = val;
    if (tid == 0) h0s = hv;
    __syncthreads();
    float prefix = 0.f, total = 0.f;
#pragma unroll
    for (int w2 = 0; w2 < 4; ++w2) {
        const float ws = wsum[w2];
        if (w2 < (tid >> 6)) prefix += ws;
        total += ws;
    }
    val += prefix;
    const float inv  = 1.0f / (total + EPS);
    const float cdf0 = h0s * inv;
    cdfnp[tid + 13] = (val * inv - cdf0) / (1.0f - cdf0 + EPS);
    __syncthreads();

    // ---- Phase 8: output LUT, register-blocked per (r, t) ----
    // T[16u+r] = (sum_p wtE[16p+r]*cdfn[u-p+13]) / (sum_p wtE[16p+r]*valid[u-p+13] + EPS)
    {
        float creg[42], oreg[42];
        const int base = 16 * t;
#pragma unroll
        for (int k = 0; k < 42; ++k) { creg[k] = cdfnp[base + k]; oreg[k] = onesp[base + k]; }
        float acc[16], sw[16];
#pragma unroll
        for (int uu = 0; uu < 16; ++uu) { acc[uu] = 0.f; sw[uu] = 0.f; }
#pragma unroll
        for (int p = 0; p < NP; ++p) {
            const float w = wtE[16 * p + r];
#pragma unroll
            for (int uu = 0; uu < 16; ++uu) {
                const int k = uu - p + 26;   // in [0,42)
                acc[uu] += w * creg[k];
                sw[uu]  += w * oreg[k];
            }
        }
#pragma unroll
        for (int uu = 0; uu < 16; ++uu)
            U.Tl[16 * (16 * t + uu) + r] = acc[uu] / (sw[uu] + EPS);
    }
    __syncthreads();

    // ---- Phase 9: equalize register-resident pixels via LUT lerp ----
    float4* ob = (float4*)(out + (size_t)b * HW + (size_t)s * 4096);
#pragma unroll
    for (int i = 0; i < 4; ++i) {
        const float4 v = px[i];
        const float vv[4] = {v.x, v.y, v.z, v.w};
        float res[4];
#pragma unroll
        for (int k2 = 0; k2 < 4; ++k2) {
            const float u = vv[k2] * 4080.f;
            int q = (int)u;
            q = min(max(q, 0), Q - 2);
            const float frac = u - (float)q;
            const float t0 = U.Tl[q], t1 = U.Tl[q + 1];
            res[k2] = fmaf(frac, t1 - t0, t0);
        }
        ob[i * 256 + tid] = make_float4(res[0], res[1], res[2], res[3]);
    }
}

extern "C" void kernel_launch(void* const* d_in, const int* in_sizes, int n_in,
                              void* d_out, int out_size, void* d_ws, size_t ws_size,
                              hipStream_t stream) {
    const float* x = (const float*)d_in[0];
    float* out     = (float*)d_out;
    const int B    = in_sizes[0] / HW;   // = 4
    const int nblk = 64 * B;             // 256 blocks <= 256 CUs -> co-resident

    unsigned int* c     = (unsigned int*)d_ws;   // B*4096 counts
    unsigned int* flags = c + (size_t)B * QSTRIDE;  // nblk arrival flags

    // zero counts + flags every launch (graph-captured; flags must be deterministic)
    hipMemsetAsync(c, 0, ((size_t)B * QSTRIDE + nblk) * sizeof(unsigned int), stream);

    fused_equalize<<<nblk, 256, 0, stream>>>(x, c, flags, out, nblk);
}

// Round 5
// 78.189 us; speedup vs baseline: 1.0200x; 1.0200x over previous
//
#include <hip/hip_runtime.h>
#include <math.h>

#define N_BINS 256
#define TAU 0.01f
#define EPS 1e-10f
#define HW (512*512)
#define Q 4081            // quant levels; Q-1 = 4080 = 16*255 so t_q - b_j = (q-16j)/4080
#define QSTRIDE 4096
#define MWIN 208          // |q-16j| <= 208 -> dropped weight exp(-13) ~ 2e-6 (negligible)
#define WTAB (2*MWIN+1)   // 417
#define WPADN 432         // 16*27, zero-padded tail
#define NP 27             // taps per phase: m = 16*(p-13)+r
#define CFP_STRIDE 289    // odd-ish stride -> 2-way bank aliasing only (free)
#define NPART 64          // hist partials per batch

// -------- Pass A: per-block partial hard histogram, NO atomics to global --------
// grid: (64, B), block 256. Each block: 1024 float4 = 4096 px -> 4096-bin partial.
__global__ __launch_bounds__(256) void hist_part_kernel(const float* __restrict__ x,
                                                        float* __restrict__ part) {
    __shared__ unsigned int lh[QSTRIDE];
    const int b   = blockIdx.y;
    const int s   = blockIdx.x;
    const int tid = threadIdx.x;
    for (int i = tid; i < QSTRIDE; i += 256) lh[i] = 0u;
    __syncthreads();

    const float4* xb = (const float4*)(x + (size_t)b * HW + (size_t)s * 4096);
#pragma unroll
    for (int i = 0; i < 4; ++i) {
        const float4 v = xb[i * 256 + tid];
        int q0 = __float2int_rn(v.x * 4080.f);
        int q1 = __float2int_rn(v.y * 4080.f);
        int q2 = __float2int_rn(v.z * 4080.f);
        int q3 = __float2int_rn(v.w * 4080.f);
        q0 = min(max(q0, 0), Q - 1); q1 = min(max(q1, 0), Q - 1);
        q2 = min(max(q2, 0), Q - 1); q3 = min(max(q3, 0), Q - 1);
        atomicAdd(&lh[q0], 1u); atomicAdd(&lh[q1], 1u);
        atomicAdd(&lh[q2], 1u); atomicAdd(&lh[q3], 1u);
    }
    __syncthreads();
    // coalesced float4 stores of the partial histogram (overwrites poison; no memset needed)
    float4* pb = (float4*)(part + ((size_t)b * NPART + s) * QSTRIDE);
#pragma unroll
    for (int k = 0; k < 4; ++k) {
        const int i4 = k * 256 + tid;          // float4 index
        pb[i4] = make_float4((float)lh[4 * i4], (float)lh[4 * i4 + 1],
                             (float)lh[4 * i4 + 2], (float)lh[4 * i4 + 3]);
    }
}

// -------- Pass B: reduce partials -> conv -> scan -> cdfn -> float2 LUT --------
// grid: B blocks, 1024 threads. Register-blocked phase decomposition (r = q mod 16).
__global__ __launch_bounds__(1024) void cdf_lut_kernel(const float* __restrict__ part,
                                                       float2* __restrict__ T2) {
    __shared__ float cfp[16 * CFP_STRIDE];   // phase-transposed padded counts (~18.5 KB)
    __shared__ float ph[256 * 17];           // conv partials [j][r] (~17.4 KB)
    __shared__ float Tl[QSTRIDE];            // output LUT (16 KB)
    __shared__ float wtE[WPADN];
    __shared__ float cdfnp[288];             // cdfn[j] at idx j+13, zero-padded
    __shared__ float onesp[288];
    __shared__ float wsum[4];
    __shared__ float h0s;
    const int b   = blockIdx.x;
    const int tid = threadIdx.x;
    const int r   = tid & 15;
    const int t2  = tid >> 4;                // 0..63

    for (int i = tid; i < 16 * CFP_STRIDE; i += 1024) cfp[i] = 0.f;
    for (int i = tid; i < 288; i += 1024) {
        cdfnp[i] = 0.f;
        onesp[i] = (i >= 13 && i < 269) ? 1.f : 0.f;
    }
    if (tid < WPADN) {
        const float d = (float)(tid - MWIN) * (1.0f / 4080.f);
        wtE[tid] = (tid < WTAB) ? __expf(-d * d * (1.0f / (2.0f * TAU * TAU))) : 0.f;
    }
    __syncthreads();

    // reduce 64 partials: thread t handles bins 4t..4t+3 (coalesced float4 streams)
    {
        const float4* pb = (const float4*)(part + (size_t)b * NPART * QSTRIDE);
        float4 acc = make_float4(0.f, 0.f, 0.f, 0.f);
        for (int p = 0; p < NPART; ++p) {
            const float4 v = pb[p * (QSTRIDE / 4) + tid];
            acc.x += v.x; acc.y += v.y; acc.z += v.z; acc.w += v.w;
        }
        const int q0 = 4 * tid;
        const float a[4] = {acc.x, acc.y, acc.z, acc.w};
#pragma unroll
        for (int j = 0; j < 4; ++j) {
            const int q = q0 + j;
            cfp[(q & 15) * CFP_STRIDE + (q >> 4) + 13] = a[j];
        }
    }
    __syncthreads();

    // conv: hist[j] = sum_r sum_p wtE[16p+r] * cfp[r][j+p]; thread (r,t2) does 4 bins
    {
        float creg[30];
        const float* cbase = &cfp[r * CFP_STRIDE + 4 * t2];
#pragma unroll
        for (int k = 0; k < 30; ++k) creg[k] = cbase[k];
        float acc[4] = {0.f, 0.f, 0.f, 0.f};
#pragma unroll
        for (int p = 0; p < NP; ++p) {
            const float w = wtE[16 * p + r];
#pragma unroll
            for (int uu = 0; uu < 4; ++uu) acc[uu] += w * creg[uu + p];
        }
#pragma unroll
        for (int uu = 0; uu < 4; ++uu) ph[(4 * t2 + uu) * 17 + r] = acc[uu];
    }
    __syncthreads();

    // phase-reduce + wave-shuffle scan over 256 bins (threads 0..255)
    if (tid < N_BINS) {
        float hv = 0.f;
#pragma unroll
        for (int rr = 0; rr < 16; ++rr) hv += ph[tid * 17 + rr];
        float val = hv;
        const int lane = tid & 63;
#pragma unroll
        for (int d = 1; d < 64; d <<= 1) {
            const float n = __shfl_up(val, (unsigned)d, 64);
            if (lane >= d) val += n;
        }
        if (lane == 63) wsum[tid >> 6] = val;
        if (tid == 0) h0s = hv;
        // stash inclusive-scan value
        ph[tid * 17 + 16] = val;
    }
    __syncthreads();
    if (tid < N_BINS) {
        float val = ph[tid * 17 + 16];
        float prefix = 0.f, total = 0.f;
#pragma unroll
        for (int w2 = 0; w2 < 4; ++w2) {
            const float ws = wsum[w2];
            if (w2 < (tid >> 6)) prefix += ws;
            total += ws;
        }
        val += prefix;
        const float inv  = 1.0f / (total + EPS);
        const float cdf0 = h0s * inv;
        cdfnp[tid + 13] = (val * inv - cdf0) / (1.0f - cdf0 + EPS);
    }
    __syncthreads();

    // LUT: T[16u+r] = (sum_p wtE[16p+r]*cdfnp[u-p+26]) / (sum_p wtE[16p+r]*onesp[...] + EPS)
    {
        float creg[30], oreg[30];
        const int base = 4 * t2;
#pragma unroll
        for (int k = 0; k < 30; ++k) { creg[k] = cdfnp[base + k]; oreg[k] = onesp[base + k]; }
        float acc[4] = {0.f, 0.f, 0.f, 0.f}, sw[4] = {0.f, 0.f, 0.f, 0.f};
#pragma unroll
        for (int p = 0; p < NP; ++p) {
            const float w = wtE[16 * p + r];
#pragma unroll
            for (int uu = 0; uu < 4; ++uu) {
                const int k = uu - p + 26;   // in [0,30)
                acc[uu] += w * creg[k];
                sw[uu]  += w * oreg[k];
            }
        }
#pragma unroll
        for (int uu = 0; uu < 4; ++uu)
            Tl[16 * (4 * t2 + uu) + r] = acc[uu] / (sw[uu] + EPS);
    }
    __syncthreads();
    // emit float2 LUT (T[q], T[q+1]) for single-b64 lerp in pass C
    for (int qi = tid; qi < QSTRIDE; qi += 1024) {
        const float t0 = Tl[qi];
        const float t1 = Tl[min(qi + 1, Q - 1)];
        T2[b * QSTRIDE + qi] = make_float2(t0, t1);
    }
}

// -------- Pass C: per-pixel lerp, one b64 LDS read / pixel --------
// grid: (256, B), block: 256.
__global__ void equalize_lut_kernel(const float* __restrict__ x,
                                    const float2* __restrict__ T2,
                                    float* __restrict__ out) {
    __shared__ __align__(16) float2 Ts[QSTRIDE];   // 32 KB
    const int b   = blockIdx.y;
    const int tid = threadIdx.x;
    const float4* Tg  = (const float4*)(T2 + (size_t)b * QSTRIDE);
    float4*       Ts4 = (float4*)Ts;
#pragma unroll
    for (int i = 0; i < 8; ++i) Ts4[i * 256 + tid] = Tg[i * 256 + tid];
    __syncthreads();

    const float4* xb = (const float4*)(x + (size_t)b * HW);
    float4*       ob = (float4*)(out + (size_t)b * HW);
    const int idx = blockIdx.x * 256 + tid;
    const float4 v = xb[idx];
    const float vals[4] = {v.x, v.y, v.z, v.w};
    float res[4];
#pragma unroll
    for (int k = 0; k < 4; ++k) {
        const float u = vals[k] * 4080.f;
        int q = (int)u;
        q = min(max(q, 0), Q - 2);
        const float frac = u - (float)q;
        const float2 t = Ts[q];
        res[k] = fmaf(frac, t.y - t.x, t.x);
    }
    ob[idx] = make_float4(res[0], res[1], res[2], res[3]);
}

extern "C" void kernel_launch(void* const* d_in, const int* in_sizes, int n_in,
                              void* d_out, int out_size, void* d_ws, size_t ws_size,
                              hipStream_t stream) {
    const float* x = (const float*)d_in[0];
    float* out     = (float*)d_out;
    const int B    = in_sizes[0] / HW;   // = 4

    float*  part = (float*)d_ws;                                   // B*64*4096 floats (4 MB)
    float2* T2   = (float2*)(part + (size_t)B * NPART * QSTRIDE);  // B*4096 float2

    hist_part_kernel<<<dim3(NPART, B), 256, 0, stream>>>(x, part);
    cdf_lut_kernel<<<B, 1024, 0, stream>>>(part, T2);
    equalize_lut_kernel<<<dim3(HW / 4 / 256, B), 256, 0, stream>>>(x, T2, out);
}

// Round 6
// 68.979 us; speedup vs baseline: 1.1562x; 1.1335x over previous
//
#include <hip/hip_runtime.h>
#include <math.h>

#define N_BINS 256
#define TAU 0.01f
#define EPS 1e-10f
#define HW (512*512)
#define Q 4081            // quant levels; Q-1 = 4080 = 16*255 so t_q - b_j = (q-16j)/4080
#define QSTRIDE 4096
#define MWIN 208          // |q-16j| <= 208 -> dropped weight exp(-13) ~ 2e-6 (negligible)
#define WTAB (2*MWIN+1)   // 417
#define WPADN 432         // 16*27, zero-padded tail
#define NP 27             // taps per phase: m = 16*(p-13)+r
#define CFP_STRIDE 289    // odd-ish stride -> 2-way bank aliasing only (free)
#define NPART 64          // hist partials per batch

// -------- Pass A: per-block partial hard histogram (no atomics to global) --------
// grid: (64, B), block 256. Each block: 1024 float4 = 4096 px -> 4096-bin partial.
__global__ __launch_bounds__(256) void hist_part_kernel(const float* __restrict__ x,
                                                        float* __restrict__ part) {
    __shared__ unsigned int lh[QSTRIDE];
    const int b   = blockIdx.y;
    const int s   = blockIdx.x;
    const int tid = threadIdx.x;
    for (int i = tid; i < QSTRIDE; i += 256) lh[i] = 0u;
    __syncthreads();

    const float4* xb = (const float4*)(x + (size_t)b * HW + (size_t)s * 4096);
#pragma unroll
    for (int i = 0; i < 4; ++i) {
        const float4 v = xb[i * 256 + tid];
        int q0 = __float2int_rn(v.x * 4080.f);
        int q1 = __float2int_rn(v.y * 4080.f);
        int q2 = __float2int_rn(v.z * 4080.f);
        int q3 = __float2int_rn(v.w * 4080.f);
        q0 = min(max(q0, 0), Q - 1); q1 = min(max(q1, 0), Q - 1);
        q2 = min(max(q2, 0), Q - 1); q3 = min(max(q3, 0), Q - 1);
        atomicAdd(&lh[q0], 1u); atomicAdd(&lh[q1], 1u);
        atomicAdd(&lh[q2], 1u); atomicAdd(&lh[q3], 1u);
    }
    __syncthreads();
    float4* pb = (float4*)(part + ((size_t)b * NPART + s) * QSTRIDE);
#pragma unroll
    for (int k = 0; k < 4; ++k) {
        const int i4 = k * 256 + tid;
        pb[i4] = make_float4((float)lh[4 * i4], (float)lh[4 * i4 + 1],
                             (float)lh[4 * i4 + 2], (float)lh[4 * i4 + 3]);
    }
}

// -------- Pass B1: wide partial reduction -> merged counts c --------
// grid: (64, B), block 256. Block (qc,b) reduces 64 partials over its 64-bin slice.
// thread (pg=tid>>4, qg=tid&15): sums partials pg,pg+16,pg+32,pg+48 for float4 qi.
__global__ __launch_bounds__(256) void reduce_part_kernel(const float* __restrict__ part,
                                                          float* __restrict__ c) {
    __shared__ float4 red[256];
    const int b   = blockIdx.y;
    const int qc  = blockIdx.x;          // 64-bin slice: float4 indices qc*16..qc*16+15
    const int tid = threadIdx.x;
    const int pg  = tid >> 4;            // 0..15
    const int qg  = tid & 15;            // 0..15
    const int qi  = qc * 16 + qg;        // float4 index within QSTRIDE/4
    const float4* p4 = (const float4*)(part + (size_t)b * NPART * QSTRIDE);
    float4 acc = make_float4(0.f, 0.f, 0.f, 0.f);
#pragma unroll
    for (int k = 0; k < 4; ++k) {
        const float4 v = p4[(size_t)(pg + 16 * k) * (QSTRIDE / 4) + qi];
        acc.x += v.x; acc.y += v.y; acc.z += v.z; acc.w += v.w;
    }
    red[tid] = acc;
    __syncthreads();
#pragma unroll
    for (int off = 8; off >= 1; off >>= 1) {
        if (pg < off) {
            const float4 o = red[(pg + off) * 16 + qg];
            float4 a = red[tid];
            a.x += o.x; a.y += o.y; a.z += o.z; a.w += o.w;
            red[tid] = a;
        }
        __syncthreads();
    }
    if (pg == 0) ((float4*)(c + (size_t)b * QSTRIDE))[qi] = red[qg];
}

// -------- Pass B2: conv -> scan -> cdfn -> float2 LUT (1 block / batch, tiny input) --------
__global__ __launch_bounds__(1024) void cdf_lut_kernel(const float* __restrict__ c,
                                                       float2* __restrict__ T2) {
    __shared__ float cfp[16 * CFP_STRIDE];   // phase-transposed padded counts
    __shared__ float ph[256 * 17];           // conv partials [j][r]
    __shared__ float Tl[QSTRIDE];
    __shared__ float wtE[WPADN];
    __shared__ float cdfnp[288];
    __shared__ float onesp[288];
    __shared__ float wsum[4];
    __shared__ float h0s;
    const int b   = blockIdx.x;
    const int tid = threadIdx.x;
    const int r   = tid & 15;
    const int t2  = tid >> 4;                // 0..63

    for (int i = tid; i < 16 * CFP_STRIDE; i += 1024) cfp[i] = 0.f;
    for (int i = tid; i < 288; i += 1024) {
        cdfnp[i] = 0.f;
        onesp[i] = (i >= 13 && i < 269) ? 1.f : 0.f;
    }
    if (tid < WPADN) {
        const float d = (float)(tid - MWIN) * (1.0f / 4080.f);
        wtE[tid] = (tid < WTAB) ? __expf(-d * d * (1.0f / (2.0f * TAU * TAU))) : 0.f;
    }
    __syncthreads();

    // load merged counts (16 KB), scatter phase-transposed
    {
        const float4 v = ((const float4*)(c + (size_t)b * QSTRIDE))[tid];
        const int q0 = 4 * tid;
        const float a[4] = {v.x, v.y, v.z, v.w};
#pragma unroll
        for (int j = 0; j < 4; ++j) {
            const int q = q0 + j;
            cfp[(q & 15) * CFP_STRIDE + (q >> 4) + 13] = a[j];
        }
    }
    __syncthreads();

    // conv: hist[j] = sum_r sum_p wtE[16p+r] * cfp[r][j+p]; thread (r,t2) does 4 bins
    {
        float creg[30];
        const float* cbase = &cfp[r * CFP_STRIDE + 4 * t2];
#pragma unroll
        for (int k = 0; k < 30; ++k) creg[k] = cbase[k];
        float acc[4] = {0.f, 0.f, 0.f, 0.f};
#pragma unroll
        for (int p = 0; p < NP; ++p) {
            const float w = wtE[16 * p + r];
#pragma unroll
            for (int uu = 0; uu < 4; ++uu) acc[uu] += w * creg[uu + p];
        }
#pragma unroll
        for (int uu = 0; uu < 4; ++uu) ph[(4 * t2 + uu) * 17 + r] = acc[uu];
    }
    __syncthreads();

    // phase-reduce + wave-shuffle scan over 256 bins
    if (tid < N_BINS) {
        float hv = 0.f;
#pragma unroll
        for (int rr = 0; rr < 16; ++rr) hv += ph[tid * 17 + rr];
        float val = hv;
        const int lane = tid & 63;
#pragma unroll
        for (int d = 1; d < 64; d <<= 1) {
            const float n = __shfl_up(val, (unsigned)d, 64);
            if (lane >= d) val += n;
        }
        if (lane == 63) wsum[tid >> 6] = val;
        if (tid == 0) h0s = hv;
        ph[tid * 17 + 16] = val;
    }
    __syncthreads();
    if (tid < N_BINS) {
        float val = ph[tid * 17 + 16];
        float prefix = 0.f, total = 0.f;
#pragma unroll
        for (int w2 = 0; w2 < 4; ++w2) {
            const float ws = wsum[w2];
            if (w2 < (tid >> 6)) prefix += ws;
            total += ws;
        }
        val += prefix;
        const float inv  = 1.0f / (total + EPS);
        const float cdf0 = h0s * inv;
        cdfnp[tid + 13] = (val * inv - cdf0) / (1.0f - cdf0 + EPS);
    }
    __syncthreads();

    // LUT: T[16u+r] = (sum_p wtE[16p+r]*cdfnp[u-p+26]) / (sum_p wtE[16p+r]*onesp[...] + EPS)
    {
        float creg[30], oreg[30];
        const int base = 4 * t2;
#pragma unroll
        for (int k = 0; k < 30; ++k) { creg[k] = cdfnp[base + k]; oreg[k] = onesp[base + k]; }
        float acc[4] = {0.f, 0.f, 0.f, 0.f}, sw[4] = {0.f, 0.f, 0.f, 0.f};
#pragma unroll
        for (int p = 0; p < NP; ++p) {
            const float w = wtE[16 * p + r];
#pragma unroll
            for (int uu = 0; uu < 4; ++uu) {
                const int k = uu - p + 26;
                acc[uu] += w * creg[k];
                sw[uu]  += w * oreg[k];
            }
        }
#pragma unroll
        for (int uu = 0; uu < 4; ++uu)
            Tl[16 * (4 * t2 + uu) + r] = acc[uu] / (sw[uu] + EPS);
    }
    __syncthreads();
    for (int qi = tid; qi < QSTRIDE; qi += 1024) {
        const float t0 = Tl[qi];
        const float t1 = Tl[min(qi + 1, Q - 1)];
        T2[b * QSTRIDE + qi] = make_float2(t0, t1);
    }
}

// -------- Pass C: per-pixel lerp, one b64 LDS read / pixel --------
__global__ void equalize_lut_kernel(const float* __restrict__ x,
                                    const float2* __restrict__ T2,
                                    float* __restrict__ out) {
    __shared__ __align__(16) float2 Ts[QSTRIDE];
    const int b   = blockIdx.y;
    const int tid = threadIdx.x;
    const float4* Tg  = (const float4*)(T2 + (size_t)b * QSTRIDE);
    float4*       Ts4 = (float4*)Ts;
#pragma unroll
    for (int i = 0; i < 8; ++i) Ts4[i * 256 + tid] = Tg[i * 256 + tid];
    __syncthreads();

    const float4* xb = (const float4*)(x + (size_t)b * HW);
    float4*       ob = (float4*)(out + (size_t)b * HW);
    const int idx = blockIdx.x * 256 + tid;
    const float4 v = xb[idx];
    const float vals[4] = {v.x, v.y, v.z, v.w};
    float res[4];
#pragma unroll
    for (int k = 0; k < 4; ++k) {
        const float u = vals[k] * 4080.f;
        int q = (int)u;
        q = min(max(q, 0), Q - 2);
        const float frac = u - (float)q;
        const float2 t = Ts[q];
        res[k] = fmaf(frac, t.y - t.x, t.x);
    }
    ob[idx] = make_float4(res[0], res[1], res[2], res[3]);
}

extern "C" void kernel_launch(void* const* d_in, const int* in_sizes, int n_in,
                              void* d_out, int out_size, void* d_ws, size_t ws_size,
                              hipStream_t stream) {
    const float* x = (const float*)d_in[0];
    float* out     = (float*)d_out;
    const int B    = in_sizes[0] / HW;   // = 4

    float*  part = (float*)d_ws;                                   // B*64*4096 floats (4 MB)
    float*  c    = part + (size_t)B * NPART * QSTRIDE;             // B*4096 floats
    float2* T2   = (float2*)(c + (size_t)B * QSTRIDE);             // B*4096 float2

    hist_part_kernel<<<dim3(NPART, B), 256, 0, stream>>>(x, part);
    reduce_part_kernel<<<dim3(64, B), 256, 0, stream>>>(part, c);
    cdf_lut_kernel<<<B, 1024, 0, stream>>>(c, T2);
    equalize_lut_kernel<<<dim3(HW / 4 / 256, B), 256, 0, stream>>>(x, T2, out);
}